// Round 9
// baseline (124.299 us; speedup 1.0000x reference)
//
#include <hip/hip_runtime.h>

// AttentionLayer: out = softmax(Q @ V^T) @ V ; B=4, SQ=SKV=4096, D=64, fp32.
//
// R22: BARRIER-FREE main loop (direct global->register operands) on R20 body.
// LESSON (R14/R15): absmax tolerance 0.03125 has ZERO numeric headroom; only
// bit-exact transforms admissible. S pinned to 4.
// R17-R21 post-mortem: four neutral intra-wave scheduling rounds. Wall per
// block-iter ~6400cy vs ~2700cy summed pipe work: __syncthreads every 64-kv
// tile phase-LOCKS all 16 waves/CU (all in softmax -> matrix idle; all in
// MFMA -> VALU/TRANS idle). The barrier existed only because global_load_lds
// staging made waves read tiles DMA'd by other waves.
// R22 change (bit-exact: identical operand bits, identical FP op order):
//   Main loop reads operands DIRECTLY from vh/vt (swizzles are baked into
//   the global layouts by prep; verified LDS==global mapping):
//     A(nf,kc):  gv  + (kv0+it*64+nf*16+col)*64 + ch*8
//     V(nf2,kc): gvt + (nf2*16+col)*SKV + kv0+it*64 + ch*8
//   kr[8] = S^T operands prefetched one tile ahead; vr[8] = PV operands
//   staged end-of-iter (as R20). Loads issued BEFORE the exp2 phase so L2
//   latency (~250cy) hides under it. NO barriers in the main loop -> waves
//   free-run and phase-stagger; L1 absorbs the 4-waves-same-tile reuse
//   (complementary kc chunk pairs consume each 128B line within one wave).
//   LDS now only the 18KB epilogue transpose buffer (1 barrier).
// Kept: XCD swizzle (FETCH 12.3->6.2MB, R19), R20 body order (passed,
// bit-exact), lazy exact rescale, v_max3 tree, setprio, combine/prep as-is.
// R12 lesson: no __threadfence per block (L2 writeback storm, 7x).

#define NB   4
#define SQ   4096
#define SKV  4096
#define DH   64
#define L2E  1.44269504088896340736f

typedef _Float16 half8 __attribute__((ext_vector_type(8)));
typedef _Float16 half4 __attribute__((ext_vector_type(4)));
typedef _Float16 half2v __attribute__((ext_vector_type(2)));
typedef float f32x4 __attribute__((ext_vector_type(4)));
typedef unsigned short u16;

#define MFMA16(a, b, c) __builtin_amdgcn_mfma_f32_16x16x16f16((a), (b), (c), 0, 0, 0)
#define MFMA32(a, b, c) __builtin_amdgcn_mfma_f32_16x16x32_f16((a), (b), (c), 0, 0, 0)

__device__ __forceinline__ u16 f2h(float f) {
  _Float16 h = (_Float16)f;
  return __builtin_bit_cast(u16, h);
}
__device__ __forceinline__ half2v pkrtz(float a, float b) {
  return __builtin_bit_cast(half2v, __builtin_amdgcn_cvt_pkrtz(a, b));
}
__device__ __forceinline__ float fmax3(float a, float b, float c) {
  return fmaxf(fmaxf(a, b), c);   // clang fuses to v_max3_f32
}

// ---------------------------------------------------------------- prep ----
// V fp32 -> vh fp16 [b][j][d-chunks swizzled by j&7]
//        -> vt fp16 [b][d][per-64-tile: phys chunk h^(d&7), h=(kc2*4+quad),
//                    elem e: kv = kc2*32+(e>>2)*16+quad*4+(e&3)]
// XCD swizzle: b = (blk&7)>>1 (batch pinned to XCD pair), rem re-derived.
__global__ __launch_bounds__(256) void prep_kernel(
    const float* __restrict__ V, u16* __restrict__ vh, u16* __restrict__ vt) {
  __shared__ u16 ldsT[16 * 72];
  int blk = blockIdx.x;
  int x   = blk & 7;                 // XCD under round-robin dispatch
  int b   = x >> 1;
  int rem = ((x & 1) << 7) + (blk >> 3);   // 0..255 within b (bijective)
  int j0  = (rem >> 2) << 6;   // kv tile base
  int d0  = (rem & 3) << 4;    // d tile base
  int t   = threadIdx.x;
  int j   = t >> 2;            // 0..63
  int dc  = (t & 3) << 2;      // 0,4,8,12

  const float* src = V + ((size_t)(b * SKV) + j0 + j) * DH + d0 + dc;
  float4 v4 = *(const float4*)src;
  u16 h[4] = {f2h(v4.x), f2h(v4.y), f2h(v4.z), f2h(v4.w)};
  unsigned p0 = (unsigned)h[0] | ((unsigned)h[1] << 16);
  unsigned p1 = (unsigned)h[2] | ((unsigned)h[3] << 16);
  int dfull = d0 + dc;
  int physd = ((((dfull >> 3) ^ (j & 7)) << 3)) + (dfull & 7);
  *(uint2*)(vh + ((size_t)(b * SKV) + j0 + j) * DH + physd) = make_uint2(p0, p1);

#pragma unroll
  for (int k = 0; k < 4; ++k) ldsT[(dc + k) * 72 + j] = h[k];
  __syncthreads();

  int dl = t >> 4;             // 0..15
  int jc = (t & 15) << 2;      // 0..60 (4 consecutive kv)
  u16 tr[4];
#pragma unroll
  for (int k = 0; k < 4; ++k) tr[k] = ldsT[dl * 72 + jc + k];
  unsigned q0 = (unsigned)tr[0] | ((unsigned)tr[1] << 16);
  unsigned q1 = (unsigned)tr[2] | ((unsigned)tr[3] << 16);
  int d   = d0 + dl;
  int kc2 = jc >> 5;
  int g   = (jc >> 4) & 1;
  int qd  = (jc >> 2) & 3;
  int hp  = ((kc2 << 2) | qd) ^ (d & 7);
  *(uint2*)(vt + ((size_t)(b * DH) + d) * SKV + j0 + (hp << 3) + (g << 2)) =
      make_uint2(q0, q1);
}

// ---------------------------------------------------------------- attn ----
// grid NB*64*S blocks, 256 threads = 4 waves * 16 q-cols each (64 q/block).
// Main loop has NO barriers and NO LDS: all operands direct from L2/L1.
__global__ __launch_bounds__(256, 3) void attn_kernel(
    const float* __restrict__ Q,
    const u16* __restrict__ vh,
    const u16* __restrict__ vt,
    u16* __restrict__ po,    // [NB*64*S][64 q][64 d] fp16 unnormalized O
    float* __restrict__ pm,  // [NB*64*S][64] running max (log2 domain)
    float* __restrict__ pl,  // [NB*64*S][64] running sum
    int S, int kvLen) {
  __shared__ __align__(16) u16 tpl[64 * 72];   // epilogue transpose only

  int blk  = blockIdx.x;
  int tile, s;
  if (S == 4) {
    // XCD swizzle: batch b pinned to XCD pair (b = (blk&7)>>1); within b,
    // index j = 0..255 -> (qtile, s). Bijective over 1024 blocks.
    int x  = blk & 7;
    int jj = ((x & 1) << 7) + (blk >> 3);   // 0..255
    tile   = ((x >> 1) << 6) + (jj >> 2);   // b*64 + qtile
    s      = jj & 3;
  } else {
    tile = blk / S;
    s    = blk - tile * S;
  }
  int b    = tile >> 6;
  int q0   = (tile & 63) << 6;
  int kv0  = s * kvLen;
  int t    = threadIdx.x;
  int wave = t >> 6;
  int lane = t & 63;
  int col  = lane & 15;
  int quad = lane >> 4;
  int qw   = q0 + (wave << 4);
  int c7   = col & 7;
  int ch0  = quad ^ c7;
  int ch1  = ch0 ^ 4;

  const u16* gv  = vh + (size_t)(b * SKV) * DH;
  const u16* gvt = vt + (size_t)(b * DH) * SKV;

  // ---- Q fragment as B-operand (n=col=q, k=quad*8+j), log2e folded
  half8 qf[2];
#pragma unroll
  for (int kc = 0; kc < 2; ++kc) {
    const float* qp = Q + ((size_t)(b * SQ) + qw + col) * DH + kc * 32 + (quad << 3);
    float4 a0 = *(const float4*)qp;
    float4 a1 = *(const float4*)(qp + 4);
    half8 hq;
    hq[0] = (_Float16)(a0.x * L2E); hq[1] = (_Float16)(a0.y * L2E);
    hq[2] = (_Float16)(a0.z * L2E); hq[3] = (_Float16)(a0.w * L2E);
    hq[4] = (_Float16)(a1.x * L2E); hq[5] = (_Float16)(a1.y * L2E);
    hq[6] = (_Float16)(a1.z * L2E); hq[7] = (_Float16)(a1.w * L2E);
    qf[kc] = hq;
  }

  f32x4 o[4];                  // O^T frags: d = nf2*16+quad*4+r, q = col
#pragma unroll
  for (int nf = 0; nf < 4; ++nf) o[nf] = (f32x4){0.f, 0.f, 0.f, 0.f};
  float m_r = -1e30f, l_r = 0.f;

  half4 pf[4];                 // P^T frags of CURRENT tile (consumed next iter)
  half8 vr[8];                 // PV operands of CURRENT tile (next iter's PV)
  half8 kr[8];                 // S^T operands of NEXT tile (prefetched)

  // ---- per-lane global operand pointers (verified == LDS-path values):
  //   A(nf,kc0): paw0 + it*4096 + nf*1024 ; kc1: paw1 ...
  //   V(nf2,kc0): pvw0 + it*64 + nf2*16*SKV ; kc1: pvw1 ...
  const u16* paw0 = gv + ((size_t)(kv0 + col) << 6) + (ch0 << 3);
  const u16* paw1 = gv + ((size_t)(kv0 + col) << 6) + (ch1 << 3);
  const u16* pvw0 = gvt + (size_t)col * SKV + kv0 + (ch0 << 3);
  const u16* pvw1 = gvt + (size_t)col * SKV + kv0 + (ch1 << 3);

  // prologue: prefetch S^T operands of tile 0
#pragma unroll
  for (int nf = 0; nf < 4; ++nf) {
    kr[nf]     = *(const half8*)(paw0 + (nf << 10));
    kr[4 + nf] = *(const half8*)(paw1 + (nf << 10));
  }
  paw0 += 4096; paw1 += 4096;  // -> tile 1

  int nIter = kvLen >> 6;      // 16 at S=4

  for (int it = 0; it < nIter; ++it) {
    // ---- A(t): S^T = V @ Q^T from kr ; sf[nf] covers kv = nf*16+quad*4+r
    f32x4 sf[4];
#pragma unroll
    for (int nf = 0; nf < 4; ++nf) sf[nf] = (f32x4){0.f, 0.f, 0.f, 0.f};
    __builtin_amdgcn_s_setprio(1);
#pragma unroll
    for (int nf = 0; nf < 4; ++nf) {
      sf[nf] = MFMA32(kr[nf],     qf[0], sf[nf]);
      sf[nf] = MFMA32(kr[4 + nf], qf[1], sf[nf]);
    }
    __builtin_amdgcn_s_setprio(0);

    // ---- local max tree (value-identical chain), shfls interleaved with
    //      PV(t-1) halves so DS round-trips hide under the matrix pipe (R20).
    float t0 = fmax3(sf[0][0], sf[0][1], sf[0][2]);
    float t1 = fmax3(sf[0][3], sf[1][0], sf[1][1]);
    float t2 = fmax3(sf[1][2], sf[1][3], sf[2][0]);
    float t3 = fmax3(sf[2][1], sf[2][2], sf[2][3]);
    float t4 = fmax3(sf[3][0], sf[3][1], sf[3][2]);
    float t5 = fmax3(t0, t1, sf[3][3]);
    float tmw = fmax3(t2, t3, t4);
    tmw = fmaxf(tmw, t5);
    float tx = __shfl_xor(tmw, 16, 64);      // issue shfl #1

    if (it > 0) {                            // PV(t-1) half kc2=0
      __builtin_amdgcn_s_setprio(1);
#pragma unroll
      for (int nf2 = 0; nf2 < 4; ++nf2) {
        half8 w8 = vr[nf2];
        half4 wlo = __builtin_shufflevector(w8, w8, 0, 1, 2, 3);
        half4 whi = __builtin_shufflevector(w8, w8, 4, 5, 6, 7);
        o[nf2] = MFMA16(wlo, pf[0], o[nf2]);
        o[nf2] = MFMA16(whi, pf[1], o[nf2]);
      }
      __builtin_amdgcn_s_setprio(0);
    }

    float tm2 = fmaxf(tmw, tx);
    float ty = __shfl_xor(tm2, 32, 64);      // issue shfl #2

    if (it > 0) {                            // PV(t-1) half kc2=1
      __builtin_amdgcn_s_setprio(1);
#pragma unroll
      for (int nf2 = 0; nf2 < 4; ++nf2) {
        half8 w8 = vr[4 + nf2];
        half4 wlo = __builtin_shufflevector(w8, w8, 0, 1, 2, 3);
        half4 whi = __builtin_shufflevector(w8, w8, 4, 5, 6, 7);
        o[nf2] = MFMA16(wlo, pf[2], o[nf2]);
        o[nf2] = MFMA16(whi, pf[3], o[nf2]);
      }
      __builtin_amdgcn_s_setprio(0);
    }

    // ---- V: issue next operand loads NOW (kr/vr consumed above; their
    //      ~250cy L2 latency hides under the exp2/pack phase below).
    //      vr <- PV operands of tile t (used next iter); kr <- S^T of t+1.
#pragma unroll
    for (int nf2 = 0; nf2 < 4; ++nf2) {
      vr[nf2]     = *(const half8*)(pvw0 + nf2 * (16 * SKV));
      vr[4 + nf2] = *(const half8*)(pvw1 + nf2 * (16 * SKV));
    }
    pvw0 += 64; pvw1 += 64;
    if (it + 1 < nIter) {
#pragma unroll
      for (int nf = 0; nf < 4; ++nf) {
        kr[nf]     = *(const half8*)(paw0 + (nf << 10));
        kr[4 + nf] = *(const half8*)(paw1 + (nf << 10));
      }
    }
    paw0 += 4096; paw1 += 4096;

    // ---- softmax finish: exact R20 values; lazy (bit-exact) rescale with
    //      the o-muls LAST so their wait on PV's o-writes hides under exp2.
    {
      float tm = fmaxf(tm2, ty);
      float mn = fmaxf(m_r, tm);
      float al = 1.0f;
      bool need = !__all(mn == m_r);  // skip => al==1.0 exactly: o*1, l*1
      if (need) {
        al = exp2f(m_r - mn);
        m_r = mn;
      }
      float rs = 0.f;
#pragma unroll
      for (int nf = 0; nf < 4; ++nf) {
        float p0 = exp2f(sf[nf][0] - mn);
        float p1 = exp2f(sf[nf][1] - mn);
        float p2 = exp2f(sf[nf][2] - mn);
        float p3 = exp2f(sf[nf][3] - mn);
        rs += (p0 + p1) + (p2 + p3);
        half2v lo = pkrtz(p0, p1);
        half2v hi = pkrtz(p2, p3);
        pf[nf] = __builtin_shufflevector(lo, hi, 0, 1, 2, 3);
      }
      if (need) {
#pragma unroll
        for (int nf = 0; nf < 4; ++nf)
#pragma unroll
          for (int r = 0; r < 4; ++r) o[nf][r] *= al;
      }
      l_r = l_r * al + rs;
    }
  }

  // ---- drain: PV for the last tile
  __builtin_amdgcn_s_setprio(1);
#pragma unroll
  for (int kc2 = 0; kc2 < 2; ++kc2) {
#pragma unroll
    for (int nf2 = 0; nf2 < 4; ++nf2) {
      half8 w8 = vr[kc2 * 4 + nf2];
      half4 wlo = __builtin_shufflevector(w8, w8, 0, 1, 2, 3);
      half4 whi = __builtin_shufflevector(w8, w8, 4, 5, 6, 7);
      o[nf2] = MFMA16(wlo, pf[kc2 * 2], o[nf2]);
      o[nf2] = MFMA16(whi, pf[kc2 * 2 + 1], o[nf2]);
    }
  }
  __builtin_amdgcn_s_setprio(0);

  // ---- epilogue: l reduce across quads, pm/pl, transpose O^T -> po[q][d]
  l_r += __shfl_xor(l_r, 16, 64);
  l_r += __shfl_xor(l_r, 32, 64);
  int pidx = tile * S + s;
  if (quad == 0) {
    pm[(size_t)pidx * 64 + (wave << 4) + col] = m_r;
    pl[(size_t)pidx * 64 + (wave << 4) + col] = l_r;
  }

  {
    int qrow = (wave << 4) + col;
#pragma unroll
    for (int nf2 = 0; nf2 < 4; ++nf2) {
#pragma unroll
      for (int r2 = 0; r2 < 4; r2 += 2) {
        unsigned pk = (unsigned)f2h(o[nf2][r2]) |
                      ((unsigned)f2h(o[nf2][r2 + 1]) << 16);
        int d = nf2 * 16 + (quad << 2) + r2;
        *(unsigned*)(tpl + qrow * 72 + d) = pk;
      }
    }
  }
  __syncthreads();
  {
    u16* pob = po + (size_t)pidx * 64 * 64;
    int q = t >> 2, hc = (t & 3) << 4;
    uint4 x0 = *(const uint4*)(tpl + q * 72 + hc);
    uint4 x1 = *(const uint4*)(tpl + q * 72 + hc + 8);
    *(uint4*)(pob + q * 64 + hc)     = x0;
    *(uint4*)(pob + q * 64 + hc + 8) = x1;
  }
}

// ------------------------------------------------------------- combine ----
// grid NB*SQ/32 blocks, 256 threads; thread = (q row, 8-d chunk).
// Statically unrolled (S <= 8, predicated) so mv/lv/w stay in registers;
// iteration order identical to the dynamic loop -> bit-identical at S=4.
// XCD swizzle (S==4): combine block lands on the XCD pair holding its
// tile's po/pm/pl (written by attn blocks of the same b).
__global__ __launch_bounds__(256) void combine_kernel(
    const u16* __restrict__ po,
    const float* __restrict__ pm,
    const float* __restrict__ pl,
    float* __restrict__ out, int S) {
  int t    = threadIdx.x;
  int rowg;
  if (S == 4) {
    int x  = blockIdx.x & 7;
    int j2 = ((x & 1) << 6) + (blockIdx.x >> 3);    // 0..127 within b
    int tile = ((x >> 1) << 6) + (j2 >> 1);         // b*64 + qtile
    rowg = tile * 64 + ((j2 & 1) << 5) + (t >> 3);
  } else {
    rowg = blockIdx.x * 32 + (t >> 3);
  }
  int tile = rowg >> 6;
  int row  = rowg & 63;
  int dc   = (t & 7) << 3;

  float mv[8], lv[8];
  float M = -1e30f;
#pragma unroll
  for (int s = 0; s < 8; ++s) {
    if (s < S) {
      mv[s] = pm[(size_t)(tile * S + s) * 64 + row];
      lv[s] = pl[(size_t)(tile * S + s) * 64 + row];
      M = fmaxf(M, mv[s]);
    }
  }
  float L = 0.f, w[8];
#pragma unroll
  for (int s = 0; s < 8; ++s) {
    if (s < S) {
      w[s] = exp2f(mv[s] - M);
      L += lv[s] * w[s];
    }
  }
  float acc[8] = {0.f, 0.f, 0.f, 0.f, 0.f, 0.f, 0.f, 0.f};
#pragma unroll
  for (int s = 0; s < 8; ++s) {
    if (s < S) {
      const u16* p = po + (size_t)(tile * S + s) * 4096 + row * 64 + dc;
      uint4 raw = *(const uint4*)p;
      half8 x = __builtin_bit_cast(half8, raw);
#pragma unroll
      for (int k = 0; k < 8; ++k) acc[k] += w[s] * (float)x[k];
    }
  }
  float invL = 1.0f / L;
  float* op = out + (size_t)rowg * 64 + dc;
  f32x4 o0 = (f32x4){acc[0], acc[1], acc[2], acc[3]};
  f32x4 o1 = (f32x4){acc[4], acc[5], acc[6], acc[7]};
  *(f32x4*)op       = o0 * invL;
  *(f32x4*)(op + 4) = o1 * invL;
}

// -------------------------------------------------------------- launch ----
extern "C" void kernel_launch(void* const* d_in, const int* in_sizes, int n_in,
                              void* d_out, int out_size, void* d_ws, size_t ws_size,
                              hipStream_t stream) {
  const float* Q = (const float*)d_in[0];
  const float* V = (const float*)d_in[1];
  float* out = (float*)d_out;

  const size_t convBytes = (size_t)2 * NB * SKV * DH * 2;  // vh+vt = 4 MB
  auto partBytes = [](int S) {
    return (size_t)NB * 64 * S * ((size_t)64 * 64 * 2 + 64 * 8);
  };
  // S pinned to 4: S=8 exceeded the absmax tolerance twice (R14/R15) —
  // the error budget is exactly exhausted at S=4. Do not raise.
  int S = 4;
  while (S > 1 && ws_size < convBytes + partBytes(S)) S >>= 1;
  int kvLen = SKV / S;

  u16* vh = (u16*)d_ws;
  u16* vt = vh + (size_t)NB * SKV * DH;
  u16* po = vt + (size_t)NB * SKV * DH;
  float* pm = (float*)(po + (size_t)NB * 64 * S * 64 * 64);
  float* pl = pm + (size_t)NB * 64 * S * 64;

  prep_kernel<<<NB * 256, 256, 0, stream>>>(V, vh, vt);
  attn_kernel<<<NB * 64 * S, 256, 0, stream>>>(Q, vh, vt, po, pm, pl, S, kvLen);
  combine_kernel<<<NB * SQ / 32, 256, 0, stream>>>(po, pm, pl, out, S);
}

// Round 10
// 104.127 us; speedup vs baseline: 1.1937x; 1.1937x over previous
//
#include <hip/hip_runtime.h>

// AttentionLayer: out = softmax(Q @ V^T) @ V ; B=4, SQ=SKV=4096, D=64, fp32.
//
// R23 == R16 resubmitted verbatim (best measured: 104.53 us, PASSED).
// Revert-to-best after R22's barrier-free direct-global variant REGRESSED
// (124.3 us: per-wave tile fetch = 4x read amplification; the 1-barrier/iter
// cooperative-DMA structure is forced by LDS capacity and is cheaper).
//
// Session ledger (attn ~42.5 us floor survived 6 attacks):
//  R16 PV-pipeline+lazy-exact-rescale+setprio  104.5  <- best
//  R17 VALU diet (addressing)                  104.7  neutral
//  R19 XCD swizzle (FETCH 12.3->6.2MB)         105.5  memory fixed, time flat
//  R20 shfl-under-MFMA interleave              105.4  neutral
//  R21 2-deep softmax pipeline                 105.9  neutral
//  R22 barrier-free direct-global              124.3  REFUTED
// Numerics: absmax == tolerance 0.03125 exactly at S=4; S=8 failed twice
// (R14/R15) -> zero headroom, only bit-exact transforms admissible.
// No pipe >54% busy: latency floor of the admissible structure.
//
// R16 content: R13 skeleton (transposed S^T = V*Q^T, K=16 PV from C-frags,
// per-lane softmax, dbuf LDS DMA staging, one barrier/iter) + bit-exact:
//  1. PV/softmax software pipeline (VT staged to regs; PV(t-1) at top of
//     iter t; o-register dependence keeps accumulation order).
//  2. Lazy exact rescale: skip exp2+16 o-muls iff __all(mn == m_r).
//  3. s_setprio(1) around MFMA clusters.
// R12 lesson: no __threadfence per block (L2 writeback storm, 7x).

#define NB   4
#define SQ   4096
#define SKV  4096
#define DH   64
#define L2E  1.44269504088896340736f

typedef _Float16 half8 __attribute__((ext_vector_type(8)));
typedef _Float16 half4 __attribute__((ext_vector_type(4)));
typedef _Float16 half2v __attribute__((ext_vector_type(2)));
typedef float f32x4 __attribute__((ext_vector_type(4)));
typedef unsigned short u16;

#define MFMA16(a, b, c) __builtin_amdgcn_mfma_f32_16x16x16f16((a), (b), (c), 0, 0, 0)
#define MFMA32(a, b, c) __builtin_amdgcn_mfma_f32_16x16x32_f16((a), (b), (c), 0, 0, 0)

__device__ __forceinline__ u16 f2h(float f) {
  _Float16 h = (_Float16)f;
  return __builtin_bit_cast(u16, h);
}
__device__ __forceinline__ half2v pkrtz(float a, float b) {
  return __builtin_bit_cast(half2v, __builtin_amdgcn_cvt_pkrtz(a, b));
}
__device__ __forceinline__ float fmax3(float a, float b, float c) {
  return fmaxf(fmaxf(a, b), c);   // clang fuses to v_max3_f32
}

typedef __attribute__((address_space(1))) void gvoid;
typedef __attribute__((address_space(3))) void lvoid;
__device__ __forceinline__ void dma16(const u16* g, u16* l) {
  __builtin_amdgcn_global_load_lds((gvoid*)g, (lvoid*)l, 16, 0, 0);
}

// ---------------------------------------------------------------- prep ----
// V fp32 -> vh fp16 [b][j][d-chunks swizzled by j&7]
//        -> vt fp16 [b][d][per-64-tile: phys chunk h^(d&7), h=(kc2*4+quad),
//                    elem e: kv = kc2*32+(e>>2)*16+quad*4+(e&3)]
__global__ __launch_bounds__(256) void prep_kernel(
    const float* __restrict__ V, u16* __restrict__ vh, u16* __restrict__ vt) {
  __shared__ u16 ldsT[16 * 72];
  int blk = blockIdx.x;
  int b   = blk >> 8;
  int rem = blk & 255;
  int j0  = (rem >> 2) << 6;   // kv tile base
  int d0  = (rem & 3) << 4;    // d tile base
  int t   = threadIdx.x;
  int j   = t >> 2;            // 0..63
  int dc  = (t & 3) << 2;      // 0,4,8,12

  const float* src = V + ((size_t)(b * SKV) + j0 + j) * DH + d0 + dc;
  float4 v4 = *(const float4*)src;
  u16 h[4] = {f2h(v4.x), f2h(v4.y), f2h(v4.z), f2h(v4.w)};
  unsigned p0 = (unsigned)h[0] | ((unsigned)h[1] << 16);
  unsigned p1 = (unsigned)h[2] | ((unsigned)h[3] << 16);
  int dfull = d0 + dc;
  int physd = ((((dfull >> 3) ^ (j & 7)) << 3)) + (dfull & 7);
  *(uint2*)(vh + ((size_t)(b * SKV) + j0 + j) * DH + physd) = make_uint2(p0, p1);

#pragma unroll
  for (int k = 0; k < 4; ++k) ldsT[(dc + k) * 72 + j] = h[k];
  __syncthreads();

  int dl = t >> 4;             // 0..15
  int jc = (t & 15) << 2;      // 0..60 (4 consecutive kv)
  u16 tr[4];
#pragma unroll
  for (int k = 0; k < 4; ++k) tr[k] = ldsT[dl * 72 + jc + k];
  unsigned q0 = (unsigned)tr[0] | ((unsigned)tr[1] << 16);
  unsigned q1 = (unsigned)tr[2] | ((unsigned)tr[3] << 16);
  int d   = d0 + dl;
  int kc2 = jc >> 5;
  int g   = (jc >> 4) & 1;
  int qd  = (jc >> 2) & 3;
  int hp  = ((kc2 << 2) | qd) ^ (d & 7);
  *(uint2*)(vt + ((size_t)(b * DH) + d) * SKV + j0 + (hp << 3) + (g << 2)) =
      make_uint2(q0, q1);
}

// ---------------------------------------------------------------- attn ----
// grid NB*64*S blocks, 256 threads = 4 waves * 16 q-cols each (64 q/block).
__global__ __launch_bounds__(256, 4) void attn_kernel(
    const float* __restrict__ Q,
    const u16* __restrict__ vh,
    const u16* __restrict__ vt,
    u16* __restrict__ po,    // [NB*64*S][64 q][64 d] fp16 unnormalized O
    float* __restrict__ pm,  // [NB*64*S][64] running max (log2 domain)
    float* __restrict__ pl,  // [NB*64*S][64] running sum
    int S, int kvLen) {
  __shared__ __align__(16) u16 lds[2][2][4096];  // [buf][0=V,1=VT], 32 KB

  int blk  = blockIdx.x;
  int tile = blk / S;          // b*64 + qtile
  int s    = blk - tile * S;
  int b    = tile >> 6;
  int q0   = (tile & 63) << 6;
  int kv0  = s * kvLen;
  int t    = threadIdx.x;
  int wave = t >> 6;
  int lane = t & 63;
  int col  = lane & 15;
  int quad = lane >> 4;
  int qw   = q0 + (wave << 4);
  int c7   = col & 7;

  const u16* gv  = vh + (size_t)(b * SKV) * DH;
  const u16* gvt = vt + (size_t)(b * DH) * SKV;

  int r0 = t >> 3;             // DMA row 0..31 (second instr: +32)
  int c0 = (t & 7) << 3;       // DMA chunk elem offset
  int wb = wave << 9;          // wave-uniform LDS dest base (elems)

  // ---- Q fragment as B-operand (n=col=q, k=quad*8+j), log2e folded
  half8 qf[2];
#pragma unroll
  for (int kc = 0; kc < 2; ++kc) {
    const float* qp = Q + ((size_t)(b * SQ) + qw + col) * DH + kc * 32 + (quad << 3);
    float4 a0 = *(const float4*)qp;
    float4 a1 = *(const float4*)(qp + 4);
    half8 hq;
    hq[0] = (_Float16)(a0.x * L2E); hq[1] = (_Float16)(a0.y * L2E);
    hq[2] = (_Float16)(a0.z * L2E); hq[3] = (_Float16)(a0.w * L2E);
    hq[4] = (_Float16)(a1.x * L2E); hq[5] = (_Float16)(a1.y * L2E);
    hq[6] = (_Float16)(a1.z * L2E); hq[7] = (_Float16)(a1.w * L2E);
    qf[kc] = hq;
  }

  f32x4 o[4];                  // O^T frags: d = nf2*16+quad*4+r, q = col
#pragma unroll
  for (int nf = 0; nf < 4; ++nf) o[nf] = (f32x4){0.f, 0.f, 0.f, 0.f};
  float m_r = -1e30f, l_r = 0.f;

  half4 pf[4];                 // P^T frags of CURRENT tile (consumed next iter)
  half8 vr[8];                 // staged VT frags of CURRENT tile (next iter's PV)

  // prologue: DMA tile 0 into buf 0 (drained by first barrier)
  dma16(gv + ((size_t)(kv0 + r0) << 6) + c0,       &lds[0][0][0] + wb);
  dma16(gv + ((size_t)(kv0 + r0 + 32) << 6) + c0,  &lds[0][0][0] + 2048 + wb);
  dma16(gvt + (size_t)r0 * SKV + kv0 + c0,         &lds[0][1][0] + wb);
  dma16(gvt + (size_t)(r0 + 32) * SKV + kv0 + c0,  &lds[0][1][0] + 2048 + wb);

  int nIter = kvLen >> 6;
  int cur = 0;
  for (int it = 0; it < nIter; ++it) {
    __syncthreads();           // drains prior DMA (vmcnt(0)) + buf handoff

    if ((it + 1) < nIter) {    // DMA next tile; hidden under this compute
      int j0n = kv0 + ((it + 1) << 6);
      u16* dv  = &lds[cur ^ 1][0][0];
      u16* dvt = &lds[cur ^ 1][1][0];
      dma16(gv + ((size_t)(j0n + r0) << 6) + c0,      dv + wb);
      dma16(gv + ((size_t)(j0n + r0 + 32) << 6) + c0, dv + 2048 + wb);
      dma16(gvt + (size_t)r0 * SKV + j0n + c0,        dvt + wb);
      dma16(gvt + (size_t)(r0 + 32) * SKV + j0n + c0, dvt + 2048 + wb);
    }

    const u16* sv = &lds[cur][0][0];
    const u16* st = &lds[cur][1][0];

    // ---- S^T = V @ Q^T : sf[nf] covers kv = nf*16 + quad*4 + r
    f32x4 sf[4];
#pragma unroll
    for (int nf = 0; nf < 4; ++nf) sf[nf] = (f32x4){0.f, 0.f, 0.f, 0.f};
    __builtin_amdgcn_s_setprio(1);
#pragma unroll
    for (int nf = 0; nf < 4; ++nf) {
#pragma unroll
      for (int kc = 0; kc < 2; ++kc) {
        int ch = ((kc << 2) | quad) ^ c7;
        half8 av = *(const half8*)(sv + ((nf * 16 + col) << 6) + (ch << 3));
        sf[nf] = MFMA32(av, qf[kc], sf[nf]);
      }
    }
    __builtin_amdgcn_s_setprio(0);

    // ---- PV(t-1) from staged regs: overlaps softmax(t) below in schedule.
    //      Bit-exact reorder: rescale(t) follows via o-register dependence,
    //      so accumulation order is identical to the unpipelined loop.
    if (it > 0) {
      __builtin_amdgcn_s_setprio(1);
#pragma unroll
      for (int kc2 = 0; kc2 < 2; ++kc2) {
#pragma unroll
        for (int nf2 = 0; nf2 < 4; ++nf2) {
          half8 w8 = vr[kc2 * 4 + nf2];
          half4 wlo = __builtin_shufflevector(w8, w8, 0, 1, 2, 3);
          half4 whi = __builtin_shufflevector(w8, w8, 4, 5, 6, 7);
          o[nf2] = MFMA16(wlo, pf[kc2 * 2], o[nf2]);
          o[nf2] = MFMA16(whi, pf[kc2 * 2 + 1], o[nf2]);
        }
      }
      __builtin_amdgcn_s_setprio(0);
    }

    // ---- online softmax(t): exact R13 values; lazy (bit-exact) rescale.
    {
      float t0 = fmax3(sf[0][0], sf[0][1], sf[0][2]);
      float t1 = fmax3(sf[0][3], sf[1][0], sf[1][1]);
      float t2 = fmax3(sf[1][2], sf[1][3], sf[2][0]);
      float t3 = fmax3(sf[2][1], sf[2][2], sf[2][3]);
      float t4 = fmax3(sf[3][0], sf[3][1], sf[3][2]);
      float t5 = fmax3(t0, t1, sf[3][3]);
      float tm = fmax3(t2, t3, t4);
      tm = fmaxf(tm, t5);
      tm = fmaxf(tm, __shfl_xor(tm, 16, 64));
      tm = fmaxf(tm, __shfl_xor(tm, 32, 64));
      float mn = fmaxf(m_r, tm);
      float al = 1.0f;
      if (!__all(mn == m_r)) {   // skip taken => al==1.0 exactly: o*1, l*1
        al = exp2f(m_r - mn);    //   are exact no-ops -> bit-identical skip
        m_r = mn;
#pragma unroll
        for (int nf = 0; nf < 4; ++nf)
#pragma unroll
          for (int r = 0; r < 4; ++r) o[nf][r] *= al;
      }
      float rs = 0.f;
#pragma unroll
      for (int nf = 0; nf < 4; ++nf) {
        float p0 = exp2f(sf[nf][0] - mn);
        float p1 = exp2f(sf[nf][1] - mn);
        float p2 = exp2f(sf[nf][2] - mn);
        float p3 = exp2f(sf[nf][3] - mn);
        rs += (p0 + p1) + (p2 + p3);
        half2v lo = pkrtz(p0, p1);
        half2v hi = pkrtz(p2, p3);
        pf[nf] = __builtin_shufflevector(lo, hi, 0, 1, 2, 3);
      }
      l_r = l_r * al + rs;
    }

    // ---- stage VT(t) into regs for next iter's PV (reads complete before
    //      the next barrier's lgkmcnt(0); buffer is DMA'd only at t+1's top)
#pragma unroll
    for (int kc2 = 0; kc2 < 2; ++kc2) {
#pragma unroll
      for (int nf2 = 0; nf2 < 4; ++nf2) {
        int ch = ((kc2 << 2) | quad) ^ c7;
        vr[kc2 * 4 + nf2] = *(const half8*)(st + ((nf2 * 16 + col) << 6) + (ch << 3));
      }
    }

    cur ^= 1;
  }

  // ---- drain: PV for the last tile
  __builtin_amdgcn_s_setprio(1);
#pragma unroll
  for (int kc2 = 0; kc2 < 2; ++kc2) {
#pragma unroll
    for (int nf2 = 0; nf2 < 4; ++nf2) {
      half8 w8 = vr[kc2 * 4 + nf2];
      half4 wlo = __builtin_shufflevector(w8, w8, 0, 1, 2, 3);
      half4 whi = __builtin_shufflevector(w8, w8, 4, 5, 6, 7);
      o[nf2] = MFMA16(wlo, pf[kc2 * 2], o[nf2]);
      o[nf2] = MFMA16(whi, pf[kc2 * 2 + 1], o[nf2]);
    }
  }
  __builtin_amdgcn_s_setprio(0);

  // ---- epilogue: l reduce across quads, pm/pl, transpose O^T -> po[q][d]
  l_r += __shfl_xor(l_r, 16, 64);
  l_r += __shfl_xor(l_r, 32, 64);
  int pidx = tile * S + s;
  if (quad == 0) {
    pm[(size_t)pidx * 64 + (wave << 4) + col] = m_r;
    pl[(size_t)pidx * 64 + (wave << 4) + col] = l_r;
  }

  __syncthreads();             // tile buffers free; reuse as [64 q][72]
  u16* tp = &lds[0][0][0];
  {
    int qrow = (wave << 4) + col;
#pragma unroll
    for (int nf2 = 0; nf2 < 4; ++nf2) {
#pragma unroll
      for (int r2 = 0; r2 < 4; r2 += 2) {
        unsigned pk = (unsigned)f2h(o[nf2][r2]) |
                      ((unsigned)f2h(o[nf2][r2 + 1]) << 16);
        int d = nf2 * 16 + (quad << 2) + r2;
        *(unsigned*)(tp + qrow * 72 + d) = pk;
      }
    }
  }
  __syncthreads();
  {
    u16* pob = po + (size_t)pidx * 64 * 64;
    int q = t >> 2, hc = (t & 3) << 4;
    uint4 x0 = *(const uint4*)(tp + q * 72 + hc);
    uint4 x1 = *(const uint4*)(tp + q * 72 + hc + 8);
    *(uint4*)(pob + q * 64 + hc)     = x0;
    *(uint4*)(pob + q * 64 + hc + 8) = x1;
  }
}

// ------------------------------------------------------------- combine ----
// grid NB*SQ/32 blocks, 256 threads; thread = (q row, 8-d chunk).
// Statically unrolled (S <= 8, predicated) so mv/lv/w stay in registers;
// iteration order identical to the dynamic loop -> bit-identical at S=4.
__global__ __launch_bounds__(256) void combine_kernel(
    const u16* __restrict__ po,
    const float* __restrict__ pm,
    const float* __restrict__ pl,
    float* __restrict__ out, int S) {
  int t    = threadIdx.x;
  int rowg = blockIdx.x * 32 + (t >> 3);   // global q row
  int tile = rowg >> 6;
  int row  = rowg & 63;
  int dc   = (t & 7) << 3;

  float mv[8], lv[8];
  float M = -1e30f;
#pragma unroll
  for (int s = 0; s < 8; ++s) {
    if (s < S) {
      mv[s] = pm[(size_t)(tile * S + s) * 64 + row];
      lv[s] = pl[(size_t)(tile * S + s) * 64 + row];
      M = fmaxf(M, mv[s]);
    }
  }
  float L = 0.f, w[8];
#pragma unroll
  for (int s = 0; s < 8; ++s) {
    if (s < S) {
      w[s] = exp2f(mv[s] - M);
      L += lv[s] * w[s];
    }
  }
  float acc[8] = {0.f, 0.f, 0.f, 0.f, 0.f, 0.f, 0.f, 0.f};
#pragma unroll
  for (int s = 0; s < 8; ++s) {
    if (s < S) {
      const u16* p = po + (size_t)(tile * S + s) * 4096 + row * 64 + dc;
      uint4 raw = *(const uint4*)p;
      half8 x = __builtin_bit_cast(half8, raw);
#pragma unroll
      for (int k = 0; k < 8; ++k) acc[k] += w[s] * (float)x[k];
    }
  }
  float invL = 1.0f / L;
  float* op = out + (size_t)rowg * 64 + dc;
  f32x4 o0 = (f32x4){acc[0], acc[1], acc[2], acc[3]};
  f32x4 o1 = (f32x4){acc[4], acc[5], acc[6], acc[7]};
  *(f32x4*)op       = o0 * invL;
  *(f32x4*)(op + 4) = o1 * invL;
}

// -------------------------------------------------------------- launch ----
extern "C" void kernel_launch(void* const* d_in, const int* in_sizes, int n_in,
                              void* d_out, int out_size, void* d_ws, size_t ws_size,
                              hipStream_t stream) {
  const float* Q = (const float*)d_in[0];
  const float* V = (const float*)d_in[1];
  float* out = (float*)d_out;

  const size_t convBytes = (size_t)2 * NB * SKV * DH * 2;  // vh+vt = 4 MB
  auto partBytes = [](int S) {
    return (size_t)NB * 64 * S * ((size_t)64 * 64 * 2 + 64 * 8);
  };
  // S pinned to 4: S=8 exceeded the absmax tolerance twice (R14/R15) —
  // the error budget is exactly exhausted at S=4. Do not raise.
  int S = 4;
  while (S > 1 && ws_size < convBytes + partBytes(S)) S >>= 1;
  int kvLen = SKV / S;

  u16* vh = (u16*)d_ws;
  u16* vt = vh + (size_t)NB * SKV * DH;
  u16* po = vt + (size_t)NB * SKV * DH;
  float* pm = (float*)(po + (size_t)NB * 64 * S * 64 * 64);
  float* pl = pm + (size_t)NB * 64 * S * 64;

  prep_kernel<<<NB * 256, 256, 0, stream>>>(V, vh, vt);
  attn_kernel<<<NB * 64 * S, 256, 0, stream>>>(Q, vh, vt, po, pm, pl, S, kvLen);
  combine_kernel<<<NB * SQ / 32, 256, 0, stream>>>(po, pm, pl, out, S);
}